// Round 4
// baseline (255.897 us; speedup 1.0000x reference)
//
#include <hip/hip_runtime.h>
#include <hip/hip_bf16.h>

typedef __attribute__((ext_vector_type(8))) short short8;
typedef __attribute__((ext_vector_type(4))) float f32x4;

#define H_DIM 768
#define E_EXP 16
#define T_TASK 8
#define KSEL 4
#define L_SEQ 8192
#define B_BATCH 16
#define EW_STRIDE (768*768)

#define WCT_BLOCKS 576     // 24 x 24 tiles of 32x32
#define GEMM_BLOCKS 384    // 64 m-tiles x 6 n-tiles of 128x128
#define FILL_BLOCKS 1536
#define TOTAL_BLOCKS (WCT_BLOCKS + GEMM_BLOCKS + FILL_BLOCKS)
#define AS_LD 40           // padded A-row stride in LDS
#define FLAG_OFF 1572864   // flag location in ws (past 1.18MB wct)

// Shared-memory union: wct/gating branch vs GEMM branch (raw types, no ctors)
union SMemU {
  struct {
    unsigned short As[128 * AS_LD];   // bf16 bits
    unsigned short Bs[128 * 32];      // bf16 bits
  } g;
  struct {
    float silu[T_TASK * H_DIM];
    float logits[T_TASK][E_EXP];
    float tile[32][33];
    float g_sh[KSEL];
    int   i_sh[KSEL];
  } w;
};

__device__ __forceinline__ void gload_lds16(const void* g, void* l) {
  __builtin_amdgcn_global_load_lds((const __attribute__((address_space(1))) void*)g,
                                   (__attribute__((address_space(3))) void*)l, 16, 0, 0);
}

__global__ __launch_bounds__(256) void mega_kernel(
    const float* __restrict__ x,          // x[0] rows [8192][768] f32
    const float* __restrict__ task_full,
    const float* __restrict__ gate_w,
    const float* __restrict__ gate_b,
    const float* __restrict__ expert_w,
    __hip_bfloat16* __restrict__ wct,     // ws: [768][768] bf16 (o-major)
    int* __restrict__ flag,               // ws: producer counter (memset 0/launch)
    float* __restrict__ out,              // [16][8192][768] f32
    float* __restrict__ out_tail) {       // [16 active_probs][128 one-hot]
  __shared__ SMemU sm;
  const int bid = blockIdx.x;
  const int tid = threadIdx.x;

  if (bid < WCT_BLOCKS) {
    // ---------------- gating (redundant per block, deterministic) ----------
    for (int i = tid; i < T_TASK * H_DIM; i += 256) {
      float v = task_full[i];
      sm.w.silu[i] = v / (1.f + expf(-v));
    }
    __syncthreads();
    if (tid < T_TASK * E_EXP) {
      const int t = tid >> 4, e = tid & 15;
      float a0 = 0.f, a1 = 0.f, a2 = 0.f, a3 = 0.f;
      const float* sl = &sm.w.silu[t * H_DIM];
      for (int h = 0; h < H_DIM; h += 4) {
        a0 += sl[h]     * gate_w[(h)     * E_EXP + e];
        a1 += sl[h + 1] * gate_w[(h + 1) * E_EXP + e];
        a2 += sl[h + 2] * gate_w[(h + 2) * E_EXP + e];
        a3 += sl[h + 3] * gate_w[(h + 3) * E_EXP + e];
      }
      sm.w.logits[t][e] = (a0 + a1) + (a2 + a3) + gate_b[e];
    }
    __syncthreads();
    if (tid < T_TASK) {
      const int t = tid;
      float p[E_EXP];
      float m = -1e30f;
      for (int e = 0; e < E_EXP; ++e) m = fmaxf(m, sm.w.logits[t][e]);
      float s = 0.f;
      for (int e = 0; e < E_EXP; ++e) { p[e] = expf(sm.w.logits[t][e] - m); s += p[e]; }
      const float inv = 1.f / s;
      for (int e = 0; e < E_EXP; ++e) p[e] *= inv;
      bool used[E_EXP];
      for (int e = 0; e < E_EXP; ++e) used[e] = false;
      float g[KSEL]; int sel[KSEL];
      for (int k = 0; k < KSEL; ++k) {
        float bv = -1.f; int bi = 0;
        for (int e = 0; e < E_EXP; ++e)
          if (!used[e] && p[e] > bv) { bv = p[e]; bi = e; }
        used[bi] = true; sel[k] = bi; g[k] = bv;
      }
      if (bid == 0) {
        for (int e = 0; e < E_EXP; ++e)
          out_tail[E_EXP + t * E_EXP + e] = used[e] ? 1.f : 0.f;
        if (t == 0)
          for (int e = 0; e < E_EXP; ++e) out_tail[e] = p[e];
      }
      if (t == 0)
        for (int k = 0; k < KSEL; ++k) { sm.w.g_sh[k] = g[k]; sm.w.i_sh[k] = sel[k]; }
    }
    __syncthreads();
    // ---------------- wct tile: wct[o][d] = sum_k g_k * W[idx_k][d][o] -----
    const float g0 = sm.w.g_sh[0], g1 = sm.w.g_sh[1], g2 = sm.w.g_sh[2], g3 = sm.w.g_sh[3];
    const size_t e0 = (size_t)sm.w.i_sh[0] * EW_STRIDE;
    const size_t e1 = (size_t)sm.w.i_sh[1] * EW_STRIDE;
    const size_t e2 = (size_t)sm.w.i_sh[2] * EW_STRIDE;
    const size_t e3 = (size_t)sm.w.i_sh[3] * EW_STRIDE;
    const int d0 = (bid % 24) * 32, o0 = (bid / 24) * 32;
    const int c = tid & 31;
    const int r0 = tid >> 5;  // 0..7
#pragma unroll
    for (int it = 0; it < 4; ++it) {
      const int rr = it * 8 + r0;  // d offset
      const size_t off = (size_t)(d0 + rr) * H_DIM + o0 + c;
      sm.w.tile[rr][c] = g0 * expert_w[e0 + off] + g1 * expert_w[e1 + off] +
                         g2 * expert_w[e2 + off] + g3 * expert_w[e3 + off];
    }
    __syncthreads();
#pragma unroll
    for (int it = 0; it < 4; ++it) {
      const int rr = it * 8 + r0;  // o offset
      wct[(size_t)(o0 + rr) * H_DIM + d0 + c] = __float2bfloat16(sm.w.tile[c][rr]);
    }
    // ---------------- signal: writes visible, then release-count -----------
    __threadfence();
    __syncthreads();
    if (tid == 0)
      __hip_atomic_fetch_add(flag, 1, __ATOMIC_RELEASE, __HIP_MEMORY_SCOPE_AGENT);

  } else if (bid < WCT_BLOCKS + GEMM_BLOCKS) {
    // ---------------- GEMM: C[l][o] = 1 + sum_d X[l][d]*wct[o][d] ----------
    if (tid == 0) {
      while (__hip_atomic_load(flag, __ATOMIC_ACQUIRE, __HIP_MEMORY_SCOPE_AGENT) < WCT_BLOCKS)
        __builtin_amdgcn_s_sleep(4);
    }
    __syncthreads();
    __hip_bfloat16* As = (__hip_bfloat16*)sm.g.As;
    __hip_bfloat16* Bs = (__hip_bfloat16*)sm.g.Bs;
    const int gb = bid - WCT_BLOCKS;
    const int m0 = (gb & 63) * 128;   // consecutive bids share n0
    const int n0 = (gb >> 6) * 128;
    const int lane = tid & 63;
    const int w = tid >> 6;
    const int wr = w >> 1, wc = w & 1;        // 2x2 wave grid, 64x64 each
    const int ra = tid >> 1, sa = tid & 1;    // A staging: row, 16-float seg
    const int rb = tid >> 2, sb = tid & 3;    // B staging: row, 16B seg
    const float* gx = x + (size_t)(m0 + ra) * H_DIM + sa * 16;
    const __hip_bfloat16* gb_ptr = wct + (size_t)(n0 + rb) * H_DIM + sb * 8;
    f32x4 acc[4][4] = {};
    const int arow = wr * 64 + (lane & 15);
    const int brow = wc * 64 + (lane & 15);
    const int koff = (lane >> 4) * 8;  // same k mapping for A and B -> k-perm safe
    for (int k0 = 0; k0 < H_DIM; k0 += 32) {
      gload_lds16(gb_ptr + k0,              &Bs[tid * 8]);
      gload_lds16(gb_ptr + 64 * H_DIM + k0, &Bs[2048 + tid * 8]);
      const float4 f0 = *(const float4*)(gx + k0);
      const float4 f1 = *(const float4*)(gx + k0 + 4);
      const float4 f2 = *(const float4*)(gx + k0 + 8);
      const float4 f3 = *(const float4*)(gx + k0 + 12);
      alignas(16) __hip_bfloat16 hb[16];
      hb[0]  = __float2bfloat16(f0.x); hb[1]  = __float2bfloat16(f0.y);
      hb[2]  = __float2bfloat16(f0.z); hb[3]  = __float2bfloat16(f0.w);
      hb[4]  = __float2bfloat16(f1.x); hb[5]  = __float2bfloat16(f1.y);
      hb[6]  = __float2bfloat16(f1.z); hb[7]  = __float2bfloat16(f1.w);
      hb[8]  = __float2bfloat16(f2.x); hb[9]  = __float2bfloat16(f2.y);
      hb[10] = __float2bfloat16(f2.z); hb[11] = __float2bfloat16(f2.w);
      hb[12] = __float2bfloat16(f3.x); hb[13] = __float2bfloat16(f3.y);
      hb[14] = __float2bfloat16(f3.z); hb[15] = __float2bfloat16(f3.w);
      *(uint4*)&As[ra * AS_LD + sa * 16]     = *(const uint4*)&hb[0];
      *(uint4*)&As[ra * AS_LD + sa * 16 + 8] = *(const uint4*)&hb[8];
      __syncthreads();
      short8 av[4], bv[4];
#pragma unroll
      for (int i = 0; i < 4; ++i) av[i] = *(const short8*)&As[(arow + i * 16) * AS_LD + koff];
#pragma unroll
      for (int j = 0; j < 4; ++j) bv[j] = *(const short8*)&Bs[(brow + j * 16) * 32 + koff];
#pragma unroll
      for (int i = 0; i < 4; ++i)
#pragma unroll
        for (int j = 0; j < 4; ++j)
          acc[i][j] = __builtin_amdgcn_mfma_f32_16x16x32_bf16(av[i], bv[j], acc[i][j], 0, 0, 0);
      __syncthreads();
    }
    const int crow0 = m0 + wr * 64 + (lane >> 4) * 4;
    const int ccol0 = n0 + wc * 64 + (lane & 15);
#pragma unroll
    for (int i = 0; i < 4; ++i)
#pragma unroll
      for (int j = 0; j < 4; ++j)
#pragma unroll
        for (int q = 0; q < 4; ++q)
          __builtin_nontemporal_store(
              1.0f + acc[i][j][q],
              &out[(size_t)(crow0 + i * 16 + q) * H_DIM + ccol0 + j * 16]);

  } else {
    // ---------------- fill batches 1..15 with 1.0 (non-temporal) -----------
    const int fb = bid - (WCT_BLOCKS + GEMM_BLOCKS);
    f32x4* p = (f32x4*)(out + (size_t)L_SEQ * H_DIM);
    const size_t n4 = (size_t)(B_BATCH - 1) * L_SEQ * H_DIM / 4;  // 23592960
    size_t i = (size_t)fb * 256 + tid;
    const size_t stride = (size_t)FILL_BLOCKS * 256;
    const f32x4 one = {1.f, 1.f, 1.f, 1.f};
    for (; i < n4; i += stride) __builtin_nontemporal_store(one, &p[i]);
  }
}

// ---------------------------------------------------------------- launch ----
extern "C" void kernel_launch(void* const* d_in, const int* in_sizes, int n_in,
                              void* d_out, int out_size, void* d_ws, size_t ws_size,
                              hipStream_t stream) {
  const float* x         = (const float*)d_in[0];  // [16][8192][768]
  const float* task_full = (const float*)d_in[1];  // [8][768]
  const float* gate_w    = (const float*)d_in[2];  // [768][16]
  const float* gate_b    = (const float*)d_in[3];  // [16]
  const float* expert_w  = (const float*)d_in[4];  // [16][768][768]
  float* out = (float*)d_out;

  const size_t n_out_main = (size_t)B_BATCH * L_SEQ * H_DIM;  // 100663296
  float* out_tail = out + n_out_main;

  __hip_bfloat16* wct = (__hip_bfloat16*)d_ws;               // 1.18 MB
  int* flag = (int*)((char*)d_ws + FLAG_OFF);

  hipMemsetAsync((void*)flag, 0, sizeof(int), stream);
  mega_kernel<<<TOTAL_BLOCKS, 256, 0, stream>>>(
      x, task_full, gate_w, gate_b, expert_w, wct, flag, out, out_tail);
}

// Round 5
// 119.288 us; speedup vs baseline: 2.1452x; 2.1452x over previous
//
#include <hip/hip_runtime.h>
#include <hip/hip_bf16.h>

typedef __attribute__((ext_vector_type(8))) short short8;
typedef __attribute__((ext_vector_type(4))) float f32x4;

#define H_DIM 768
#define E_EXP 16
#define T_TASK 8
#define KSEL 4
#define L_SEQ 8192
#define B_BATCH 16
#define EW_STRIDE (768*768)

#define CVT_BLOCKS 3072    // (8192*768/8)/256 uint4 stores
#define WCT_BLOCKS 576     // 24 x 24 tiles of 32x32
#define FILL1_BLOCKS 1408  // batches 1..8 (201.3 MB)
#define GEMM_BLOCKS 384    // 64 m-strips x 6 n-tiles, m-outer order
#define FILL2_BLOCKS 1472  // batches 9..15 (176.2 MB)

// ------------------------------------------------------------------ K1 ------
// blocks [0,3072): x[0] f32 -> bf16
// blocks [3072,3648): inline gating (redundant, deterministic) + wct tile
// rest: fill batches 1..8 with 1.0
__global__ __launch_bounds__(256) void k1_cvt_wct_fill(
    const float4* __restrict__ x,
    const float* __restrict__ task_full,
    const float* __restrict__ gate_w,
    const float* __restrict__ gate_b,
    const float* __restrict__ expert_w,
    __hip_bfloat16* __restrict__ wct,
    uint4* __restrict__ xb,
    float* __restrict__ out_tail,
    float4* __restrict__ fill_p, size_t fill_n4) {
  const int bid = blockIdx.x;
  const int tid = threadIdx.x;
  if (bid < CVT_BLOCKS) {
    // ---- x0 -> bf16 ----
    const int i = bid * 256 + tid;  // one uint4 = 8 bf16
    const float4 a = x[2 * i];
    const float4 b = x[2 * i + 1];
    alignas(16) __hip_bfloat16 h[8];
    h[0] = __float2bfloat16(a.x); h[1] = __float2bfloat16(a.y);
    h[2] = __float2bfloat16(a.z); h[3] = __float2bfloat16(a.w);
    h[4] = __float2bfloat16(b.x); h[5] = __float2bfloat16(b.y);
    h[6] = __float2bfloat16(b.z); h[7] = __float2bfloat16(b.w);
    xb[i] = *(const uint4*)h;
  } else if (bid < CVT_BLOCKS + WCT_BLOCKS) {
    // ---- gating (per-block redundant, deterministic) + wct tile ----
    __shared__ float silu_s[T_TASK * H_DIM];
    __shared__ float logits[T_TASK][E_EXP];
    __shared__ float g_sh[KSEL];
    __shared__ int   i_sh[KSEL];
    __shared__ float tile[32][33];
    const int wb = bid - CVT_BLOCKS;
    for (int i = tid; i < T_TASK * H_DIM; i += 256) {
      float v = task_full[i];
      silu_s[i] = v / (1.f + expf(-v));
    }
    __syncthreads();
    if (tid < T_TASK * E_EXP) {
      const int t = tid >> 4, e = tid & 15;
      float a0 = 0.f, a1 = 0.f, a2 = 0.f, a3 = 0.f;
      const float* sl = &silu_s[t * H_DIM];
      for (int h = 0; h < H_DIM; h += 4) {
        a0 += sl[h]     * gate_w[(h)     * E_EXP + e];
        a1 += sl[h + 1] * gate_w[(h + 1) * E_EXP + e];
        a2 += sl[h + 2] * gate_w[(h + 2) * E_EXP + e];
        a3 += sl[h + 3] * gate_w[(h + 3) * E_EXP + e];
      }
      logits[t][e] = (a0 + a1) + (a2 + a3) + gate_b[e];
    }
    __syncthreads();
    if (tid < T_TASK) {
      const int t = tid;
      float p[E_EXP];
      float m = -1e30f;
      for (int e = 0; e < E_EXP; ++e) m = fmaxf(m, logits[t][e]);
      float s = 0.f;
      for (int e = 0; e < E_EXP; ++e) { p[e] = expf(logits[t][e] - m); s += p[e]; }
      const float inv = 1.f / s;
      for (int e = 0; e < E_EXP; ++e) p[e] *= inv;
      bool used[E_EXP];
      for (int e = 0; e < E_EXP; ++e) used[e] = false;
      float g[KSEL]; int sel[KSEL];
      for (int k = 0; k < KSEL; ++k) {
        float bv = -1.f; int bi = 0;
        for (int e = 0; e < E_EXP; ++e)
          if (!used[e] && p[e] > bv) { bv = p[e]; bi = e; }
        used[bi] = true; sel[k] = bi; g[k] = bv;
      }
      if (wb == 0) {
        for (int e = 0; e < E_EXP; ++e)
          out_tail[E_EXP + t * E_EXP + e] = used[e] ? 1.f : 0.f;
        if (t == 0)
          for (int e = 0; e < E_EXP; ++e) out_tail[e] = p[e];
      }
      if (t == 0)
        for (int k = 0; k < KSEL; ++k) { g_sh[k] = g[k]; i_sh[k] = sel[k]; }
    }
    __syncthreads();
    const float g0 = g_sh[0], g1 = g_sh[1], g2 = g_sh[2], g3 = g_sh[3];
    const size_t e0 = (size_t)i_sh[0] * EW_STRIDE;
    const size_t e1 = (size_t)i_sh[1] * EW_STRIDE;
    const size_t e2 = (size_t)i_sh[2] * EW_STRIDE;
    const size_t e3 = (size_t)i_sh[3] * EW_STRIDE;
    const int d0 = (wb % 24) * 32, o0 = (wb / 24) * 32;
    const int c = tid & 31;
    const int r0 = tid >> 5;  // 0..7
#pragma unroll
    for (int it = 0; it < 4; ++it) {
      const int rr = it * 8 + r0;  // d offset
      const size_t off = (size_t)(d0 + rr) * H_DIM + o0 + c;
      tile[rr][c] = g0 * expert_w[e0 + off] + g1 * expert_w[e1 + off] +
                    g2 * expert_w[e2 + off] + g3 * expert_w[e3 + off];
    }
    __syncthreads();
#pragma unroll
    for (int it = 0; it < 4; ++it) {
      const int rr = it * 8 + r0;  // o offset
      wct[(size_t)(o0 + rr) * H_DIM + d0 + c] = __float2bfloat16(tile[c][rr]);
    }
  } else {
    // ---- fill batches 1..8 ----
    const int fb = bid - CVT_BLOCKS - WCT_BLOCKS;
    size_t i = (size_t)fb * 256 + tid;
    const size_t stride = (size_t)FILL1_BLOCKS * 256;
    const float4 one = make_float4(1.f, 1.f, 1.f, 1.f);
    for (; i < fill_n4; i += stride) fill_p[i] = one;
  }
}

// ------------------------------------------------------------------ K2 ------
__device__ __forceinline__ void gload_lds16(const void* g, void* l) {
  __builtin_amdgcn_global_load_lds((const __attribute__((address_space(1))) void*)g,
                                   (__attribute__((address_space(3))) void*)l, 16, 0, 0);
}

// blocks < GEMM_BLOCKS: C[l][o] = 1 + sum_d A[l][d]*Bt[o][d]
// m-outer mapping: the 6 n-tiles of one A-strip run concurrently -> A fetched
// from HBM once, re-reads hit L3 temporally. Rest: fill batches 9..15.
__global__ __launch_bounds__(256) void k2_gemm_fill(
    const __hip_bfloat16* __restrict__ A,
    const __hip_bfloat16* __restrict__ Bt,
    float* __restrict__ C,
    float4* __restrict__ fill_p, size_t fill_n4) {
  const int bid = blockIdx.x;
  const int tid = threadIdx.x;
  if (bid < GEMM_BLOCKS) {
    __shared__ __hip_bfloat16 As[128 * 32];
    __shared__ __hip_bfloat16 Bs[128 * 32];
    const int m0 = (bid / 6) * 128;   // m-outer: bids 6k..6k+5 share this A strip
    const int n0 = (bid % 6) * 128;
    const int lane = tid & 63;
    const int w = tid >> 6;
    const int wr = w >> 1, wc = w & 1;      // 2x2 wave grid, 64x64 each
    const int r = tid >> 2, s = tid & 3;    // staging: row, 16B chunk
    const __hip_bfloat16* ga = A  + (size_t)(m0 + r) * H_DIM + s * 8;
    const __hip_bfloat16* gb = Bt + (size_t)(n0 + r) * H_DIM + s * 8;
    f32x4 acc[4][4] = {};
    const int arow = wr * 64 + (lane & 15);
    const int brow = wc * 64 + (lane & 15);
    const int koff = (lane >> 4) * 8;  // same k mapping for A and B -> k-perm safe
    for (int k0 = 0; k0 < H_DIM; k0 += 32) {
      gload_lds16(ga + k0,               &As[tid * 8]);
      gload_lds16(ga + 64 * H_DIM + k0,  &As[2048 + tid * 8]);
      gload_lds16(gb + k0,               &Bs[tid * 8]);
      gload_lds16(gb + 64 * H_DIM + k0,  &Bs[2048 + tid * 8]);
      __syncthreads();
      short8 av[4], bv[4];
#pragma unroll
      for (int i = 0; i < 4; ++i) av[i] = *(const short8*)&As[(arow + i * 16) * 32 + koff];
#pragma unroll
      for (int j = 0; j < 4; ++j) bv[j] = *(const short8*)&Bs[(brow + j * 16) * 32 + koff];
#pragma unroll
      for (int i = 0; i < 4; ++i)
#pragma unroll
        for (int j = 0; j < 4; ++j)
          acc[i][j] = __builtin_amdgcn_mfma_f32_16x16x32_bf16(av[i], bv[j], acc[i][j], 0, 0, 0);
      __syncthreads();
    }
    const int crow0 = m0 + wr * 64 + (lane >> 4) * 4;
    const int ccol0 = n0 + wc * 64 + (lane & 15);
#pragma unroll
    for (int i = 0; i < 4; ++i)
#pragma unroll
      for (int j = 0; j < 4; ++j)
#pragma unroll
        for (int q = 0; q < 4; ++q)
          C[(size_t)(crow0 + i * 16 + q) * H_DIM + ccol0 + j * 16] = 1.0f + acc[i][j][q];
  } else {
    const int fb = bid - GEMM_BLOCKS;
    size_t i = (size_t)fb * 256 + tid;
    const size_t stride = (size_t)FILL2_BLOCKS * 256;
    const float4 one = make_float4(1.f, 1.f, 1.f, 1.f);
    for (; i < fill_n4; i += stride) fill_p[i] = one;
  }
}

// ---------------------------------------------------------------- launch ----
extern "C" void kernel_launch(void* const* d_in, const int* in_sizes, int n_in,
                              void* d_out, int out_size, void* d_ws, size_t ws_size,
                              hipStream_t stream) {
  const float* x         = (const float*)d_in[0];  // [16][8192][768]
  const float* task_full = (const float*)d_in[1];  // [8][768]
  const float* gate_w    = (const float*)d_in[2];  // [768][16]
  const float* gate_b    = (const float*)d_in[3];  // [16]
  const float* expert_w  = (const float*)d_in[4];  // [16][768][768]
  float* out = (float*)d_out;

  const size_t n_out_main = (size_t)B_BATCH * L_SEQ * H_DIM;  // 100663296
  float* out_tail = out + n_out_main;

  __hip_bfloat16* wct = (__hip_bfloat16*)d_ws;                          // 1.18 MB
  __hip_bfloat16* x0b = (__hip_bfloat16*)((char*)d_ws + (size_t)EW_STRIDE * 2);

  // K1: x0->bf16 | inline-gating + wct | fill batches 1..8
  const size_t fill1_n4 = (size_t)8 * L_SEQ * H_DIM / 4;
  k1_cvt_wct_fill<<<CVT_BLOCKS + WCT_BLOCKS + FILL1_BLOCKS, 256, 0, stream>>>(
      (const float4*)x, task_full, gate_w, gate_b, expert_w,
      wct, (uint4*)x0b, out_tail,
      (float4*)(out + (size_t)1 * L_SEQ * H_DIM), fill1_n4);

  // K2: GEMM (m-outer) -> out[0] with +1.0 | fill batches 9..15
  const size_t fill2_n4 = (size_t)7 * L_SEQ * H_DIM / 4;
  k2_gemm_fill<<<GEMM_BLOCKS + FILL2_BLOCKS, 256, 0, stream>>>(
      x0b, wct, out,
      (float4*)(out + (size_t)9 * L_SEQ * H_DIM), fill2_n4);
}